// Round 7
// baseline (10733.373 us; speedup 1.0000x reference)
//
#include <hip/hip_runtime.h>
#include <hip/hip_bf16.h>

// Sizes (fixed by the problem)
enum { B_ = 64, S_ = 32, V_ = 32000, HDIM = 768, NHEAD = 16, DHEAD = 48, NLAY = 3 };
#define LN_EPS 1e-5f
#define NBLK 48   // mega-kernel grid: 48 blocks x 256 thr, all co-resident on 256 CUs

typedef __bf16 bf16_t;
typedef __bf16 bf8 __attribute__((ext_vector_type(8)));
typedef __bf16 bf4v __attribute__((ext_vector_type(4)));
typedef float f4 __attribute__((ext_vector_type(4)));

__device__ __forceinline__ float sigm(float x) { return 1.f / (1.f + expf(-x)); }

__device__ __forceinline__ f4 mfma16x16x32(bf8 a, bf8 b, f4 c) {
    return __builtin_amdgcn_mfma_f32_16x16x32_bf16(a, b, c, 0, 0, 0);
}

// ---------------------------------------------------------------------------
// Merged f32->bf16 cast over up to 15 segments (one launch for all weights).
// ---------------------------------------------------------------------------
#define NSEG 15
struct CastSegs {
    const float4* src[NSEG];
    bf4v* dst[NSEG];
    unsigned n4[NSEG];
};
__global__ __launch_bounds__(256) void cast_multi(CastSegs cs) {
    const unsigned stride = gridDim.x * 256;
#pragma unroll
    for (int s = 0; s < NSEG; ++s) {
        const float4* src = cs.src[s];
        bf4v* dst = cs.dst[s];
        const unsigned n4 = cs.n4[s];
        for (unsigned i = blockIdx.x * 256 + threadIdx.x; i < n4; i += stride) {
            float4 v = src[i];
            bf4v o;
            o.x = (__bf16)v.x; o.y = (__bf16)v.y; o.z = (__bf16)v.z; o.w = (__bf16)v.w;
            dst[i] = o;
        }
    }
}

// ---------------------------------------------------------------------------
// MFMA GEMM (precompute + output head):
// C[M,N] = A[M,K](bf16) @ W[N,K](bf16)^T + bias(f32).
// A/B frag: lane l holds 8 contig K-elems of row (l&15) at k=(l>>4)*8.
// C/D frag: col = lane&15, row = (lane>>4)*4 + reg.   (HW-verified mapping)
// ---------------------------------------------------------------------------
template <int OUTBF, int REMAP>
__global__ __launch_bounds__(256) void gemm_mf(const bf16_t* __restrict__ A, int lda,
                                               const bf16_t* __restrict__ W, int ldw,
                                               const float* __restrict__ bias,
                                               void* __restrict__ Cv, int ldc, int K) {
    const int lane = threadIdx.x & 63, wv = threadIdx.x >> 6;
    const int r = lane & 15, kg = lane >> 4;
    const int m0 = blockIdx.y * 64 + wv * 16;
    const int n0 = blockIdx.x * 64;
    const bf16_t* Ar = A + (size_t)(m0 + r) * lda + kg * 8;
    const bf16_t* W0 = W + (size_t)(n0 + r) * ldw + kg * 8;
    f4 acc[4] = {};
#pragma unroll 2
    for (int k0 = 0; k0 < K; k0 += 32) {
        bf8 a = *(const bf8*)(Ar + k0);
#pragma unroll
        for (int j = 0; j < 4; ++j) {
            bf8 b = *(const bf8*)(W0 + (size_t)j * 16 * ldw + k0);
            acc[j] = mfma16x16x32(a, b, acc[j]);
        }
    }
#pragma unroll
    for (int j = 0; j < 4; ++j) {
        int n = n0 + j * 16 + r;
        float bz = bias[n];
#pragma unroll
        for (int i = 0; i < 4; ++i) {
            int m = m0 + kg * 4 + i;
            float v = acc[j][i] + bz;
            if (REMAP) {
                int tt = m >> 6, bb = m & 63;
                ((float*)Cv)[((size_t)bb * S_ + tt) * V_ + n] = v;
            } else if (OUTBF) {
                ((bf16_t*)Cv)[(size_t)m * ldc + n] = (__bf16)v;
            } else {
                ((float*)Cv)[(size_t)m * ldc + n] = v;
            }
        }
    }
}

// attn_feat (B,2048,7,7) f32 -> featb (B*49, 2048) bf16
__global__ __launch_bounds__(256) void transpose_feat(const float* __restrict__ af,
                                                      bf16_t* __restrict__ feat) {
    __shared__ float t[32][33];
    int b = blockIdx.z;
    int c0 = blockIdx.x * 32;
    int p0 = blockIdx.y * 32;
    int tx = threadIdx.x, ty = threadIdx.y;  // (32,8)
    const float* src = af + (size_t)b * 2048 * 49;
    for (int i = ty; i < 32; i += 8) {
        int c = c0 + i, p = p0 + tx;
        t[i][tx] = (p < 49) ? src[(size_t)c * 49 + p] : 0.f;
    }
    __syncthreads();
    bf16_t* dst = feat + (size_t)b * 49 * 2048;
    for (int i = ty; i < 32; i += 8) {
        int p = p0 + i, c = c0 + tx;
        if (p < 49) dst[(size_t)p * 2048 + c] = (__bf16)t[tx][i];
    }
}

// embeds gather -> bf16
__global__ void gather_emb(const int* __restrict__ ids, const float* __restrict__ emb,
                           bf16_t* __restrict__ out) {
    int r = blockIdx.x;
    int w = ids[r];
    const float* e = emb + (size_t)w * 512;
    bf16_t* o = out + (size_t)r * 512;
    for (int i = threadIdx.x; i < 512; i += 256) o[i] = (__bf16)e[i];
}

// Row-wise LayerNorm + activation (init MLPs + output head only).
__global__ __launch_bounds__(256) void ln_act(const float* __restrict__ X,
                                              const float* __restrict__ lnp,
                                              float* __restrict__ Y,
                                              bf16_t* __restrict__ Yb, int N, int act) {
    int r = blockIdx.x;
    const float* x = X + (size_t)r * N;
    float* y = Y + (size_t)r * N;
    bf16_t* yb = Yb ? (Yb + (size_t)r * N) : nullptr;
    float s1 = 0.f, s2 = 0.f;
    for (int i = threadIdx.x; i < N; i += 256) {
        float v = x[i];
        s1 += v;
        s2 += v * v;
    }
#pragma unroll
    for (int off = 32; off > 0; off >>= 1) {
        s1 += __shfl_down(s1, off, 64);
        s2 += __shfl_down(s2, off, 64);
    }
    __shared__ float a1[4], a2[4];
    __shared__ float mu_s, rs_s;
    int lane = threadIdx.x & 63, wid = threadIdx.x >> 6;
    if (lane == 0) { a1[wid] = s1; a2[wid] = s2; }
    __syncthreads();
    if (threadIdx.x == 0) {
        float S1 = a1[0] + a1[1] + a1[2] + a1[3];
        float S2 = a2[0] + a2[1] + a2[2] + a2[3];
        float mu = S1 / N;
        float var = S2 / N - mu * mu;
        mu_s = mu;
        rs_s = rsqrtf(var + LN_EPS);
    }
    __syncthreads();
    float mu = mu_s, rs = rs_s;
    for (int i = threadIdx.x; i < N; i += 256) {
        float v = (x[i] - mu) * rs * lnp[i] + lnp[N + i];
        if (act == 1) v = fmaxf(v, 0.f);
        else if (act == 2) v = tanhf(v);
        y[i] = v;
        if (yb) yb[i] = (__bf16)v;
    }
}

// Broadcast h0,c0 into all NL layers (f32 state + bf16 h).
__global__ void tile_state(const float* __restrict__ h0, const float* __restrict__ c0,
                           float* __restrict__ h, float* __restrict__ c,
                           bf16_t* __restrict__ hb) {
    int idx = blockIdx.x * 256 + threadIdx.x;
    if (idx >= B_ * HDIM) return;
    float hv = h0[idx], cv = c0[idx];
#pragma unroll
    for (int l = 0; l < NLAY; ++l) {
        h[(size_t)l * B_ * HDIM + idx] = hv;
        c[(size_t)l * B_ * HDIM + idx] = cv;
        hb[(size_t)l * B_ * HDIM + idx] = (__bf16)hv;
    }
}

// ---------------------------------------------------------------------------
// Grid barrier: monotonic counter, device-scope. All NBLK blocks co-resident.
// ---------------------------------------------------------------------------
__device__ __forceinline__ void gbar(unsigned* cnt, unsigned* bi) {
    __syncthreads();
    if (threadIdx.x == 0) {
        __threadfence();
        __hip_atomic_fetch_add(cnt, 1u, __ATOMIC_ACQ_REL, __HIP_MEMORY_SCOPE_AGENT);
        unsigned target = ++(*bi) * NBLK;
        while (__hip_atomic_load(cnt, __ATOMIC_ACQUIRE, __HIP_MEMORY_SCOPE_AGENT) < target)
            __builtin_amdgcn_s_sleep(2);
        __threadfence();
    }
    __syncthreads();
}

// ---------------------------------------------------------------------------
// Mega-kernel: entire 32-step recurrence in ONE launch.
// 48 blocks x 256 thr. Per step, 8 stages separated by grid barriers:
//   q-GEMM | attn | o-GEMM(+stats) | fus1(+stats) | fus2(+stats) | 3x LSTM(+cell)
// LN fused into consumers via per-row (sum, sumsq) stats (atomicAdd epilogues).
// stats layout: [t][k][2][64], k: 0=ctx2(attn_ln) 1=x1(fus_ln1) 2=x2(fus_ln2)
// bf16 h-state DOUBLE-BUFFERED (cur/nxt) so each layer's gate-GEMM reads the
// previous-step h while the epilogue writes the new h -- no RAW/WAR race.
// ---------------------------------------------------------------------------
__global__ __launch_bounds__(256) void mega_loop(
    const bf16_t* __restrict__ qkv_wb, const float* __restrict__ qkv_b,
    const float* __restrict__ Kf, const float* __restrict__ Vf,
    const bf16_t* __restrict__ o_wb, const float* __restrict__ o_b,
    const float* __restrict__ attn_ln,
    const bf16_t* __restrict__ emb_sb,
    const bf16_t* __restrict__ fus_w1b, const float* __restrict__ fus_b1,
    const float* __restrict__ fus_ln1,
    const bf16_t* __restrict__ fus_w2b, const float* __restrict__ fus_b2,
    const float* __restrict__ fus_ln2,
    const bf16_t* __restrict__ wihb, const bf16_t* __restrict__ whhb,
    const float* __restrict__ bih, const float* __restrict__ bhh,
    float* __restrict__ hst, float* __restrict__ cst,
    bf16_t* __restrict__ hbufA, bf16_t* __restrict__ hbufB,
    float* __restrict__ qb, bf16_t* __restrict__ ctxB, float* __restrict__ ctx2f,
    float* __restrict__ x1f, float* __restrict__ x2f,
    float* __restrict__ stats, bf16_t* __restrict__ HcB,
    unsigned* __restrict__ cnt) {
    const int tid = threadIdx.x;
    const int lane = tid & 63, wv = tid >> 6;
    const int blk = blockIdx.x;
    const int r = lane & 15, kg = lane >> 4;
    const int m0 = wv * 16;      // wave's 16 sample-rows
    const int n0 = blk * 16;     // block's 16-col n-tile (768/16 = 48 blocks)
    const size_t LBH = (size_t)B_ * HDIM;
    unsigned bi = 0;
    bf16_t* cur = hbufA;   // h(t-1), initialized by tile_state
    bf16_t* nxt = hbufB;   // receives h(t)

    for (int t = 0; t < S_; ++t) {
        // ---- St1: q = cur[2] @ Wq^T + bq -> qb (f32) ----
        {
            const bf16_t* Ar = cur + 2 * LBH + (size_t)(m0 + r) * HDIM + kg * 8;
            const bf16_t* Wr = qkv_wb + (size_t)(n0 + r) * HDIM + kg * 8;
            f4 acc = {};
#pragma unroll 4
            for (int k0 = 0; k0 < HDIM; k0 += 32)
                acc = mfma16x16x32(*(const bf8*)(Ar + k0), *(const bf8*)(Wr + k0), acc);
            const int n = n0 + r;
            const float bz = qkv_b[n];
#pragma unroll
            for (int i = 0; i < 4; ++i)
                qb[(size_t)(m0 + kg * 4 + i) * HDIM + n] = acc[i] + bz;
        }
        gbar(cnt, &bi);
        // ---- St2: attention, one (b,h) pair per wave-trip (shuffle softmax) ----
        {
            for (int p = blk * 4 + wv; p < B_ * NHEAD; p += NBLK * 4) {
                const int b = p >> 4, h = p & 15;
                const float* qrow = qb + (size_t)b * HDIM + h * DHEAD;
                float s = -1e30f;
                if (lane < 49) {
                    const float* kr = Kf + (size_t)(b * 49 + lane) * HDIM + h * DHEAD;
                    float a = 0.f;
#pragma unroll
                    for (int d = 0; d < DHEAD; ++d) a += qrow[d] * kr[d];
                    s = a * 0.14433756729740643f;  // 1/sqrt(48)
                }
                float mx = s;
#pragma unroll
                for (int o = 32; o; o >>= 1) mx = fmaxf(mx, __shfl_xor(mx, o, 64));
                const float e = (lane < 49) ? expf(s - mx) : 0.f;
                float sum = e;
#pragma unroll
                for (int o = 32; o; o >>= 1) sum += __shfl_xor(sum, o, 64);
                const float wgt = e / sum;
                float a2 = 0.f;
                const float* vb = Vf + (size_t)(b * 49) * HDIM + h * DHEAD + lane;
                for (int pp = 0; pp < 49; ++pp) {
                    const float wp = __shfl(wgt, pp, 64);
                    if (lane < DHEAD) a2 += wp * vb[(size_t)pp * HDIM];
                }
                if (lane < DHEAD) ctxB[(size_t)b * HDIM + h * DHEAD + lane] = (__bf16)a2;
            }
        }
        gbar(cnt, &bi);
        // ---- St3: ctx2_raw = ctxB @ o_w^T + o_b, + stats[0] ----
        {
            const bf16_t* Ar = ctxB + (size_t)(m0 + r) * HDIM + kg * 8;
            const bf16_t* Wr = o_wb + (size_t)(n0 + r) * HDIM + kg * 8;
            f4 acc = {};
#pragma unroll 4
            for (int k0 = 0; k0 < HDIM; k0 += 32)
                acc = mfma16x16x32(*(const bf8*)(Ar + k0), *(const bf8*)(Wr + k0), acc);
            const int n = n0 + r;
            const float bz = o_b[n];
            float* st = stats + ((size_t)t * 3 + 0) * 128;
#pragma unroll
            for (int i = 0; i < 4; ++i) {
                const int row = m0 + kg * 4 + i;
                const float v = acc[i] + bz;
                ctx2f[(size_t)row * HDIM + n] = v;
                float p1 = v, p2 = v * v;
#pragma unroll
                for (int m = 1; m < 16; m <<= 1) {
                    p1 += __shfl_xor(p1, m, 64);
                    p2 += __shfl_xor(p2, m, 64);
                }
                if (r == 0) { atomicAdd(&st[row], p1); atomicAdd(&st[64 + row], p2); }
            }
        }
        gbar(cnt, &bi);
        // ---- St4: x1_raw = [emb | LN(ctx2)] @ fus_w1^T + b1, + stats[1] ----
        {
            const int arow = m0 + r;
            const float* st0 = stats + ((size_t)t * 3 + 0) * 128;
            const float mu = st0[arow] * (1.f / HDIM);
            const float rs = rsqrtf(st0[64 + arow] * (1.f / HDIM) - mu * mu + LN_EPS);
            const float la = rs, lc = -mu * rs;
            const bf16_t* eRow = emb_sb + ((size_t)arow * S_ + t) * 512 + kg * 8;
            const float* xRow = ctx2f + (size_t)arow * HDIM + kg * 8;
            const bf16_t* Wr = fus_w1b + (size_t)(n0 + r) * 1280 + kg * 8;
            f4 acc = {};
#pragma unroll 4
            for (int k0 = 0; k0 < 1280; k0 += 32) {
                bf8 a;
                if (k0 < 512) {
                    a = *(const bf8*)(eRow + k0);
                } else {
                    const int kk = k0 - 512;
#pragma unroll
                    for (int j = 0; j < 8; ++j) {
                        const int kj = kk + kg * 8 + j;
                        a[j] = (__bf16)((xRow[kk + j] * la + lc) * attn_ln[kj] + attn_ln[HDIM + kj]);
                    }
                }
                acc = mfma16x16x32(a, *(const bf8*)(Wr + k0), acc);
            }
            const int n = n0 + r;
            const float bz = fus_b1[n];
            float* st = stats + ((size_t)t * 3 + 1) * 128;
#pragma unroll
            for (int i = 0; i < 4; ++i) {
                const int row = m0 + kg * 4 + i;
                const float v = acc[i] + bz;
                x1f[(size_t)row * HDIM + n] = v;
                float p1 = v, p2 = v * v;
#pragma unroll
                for (int m = 1; m < 16; m <<= 1) {
                    p1 += __shfl_xor(p1, m, 64);
                    p2 += __shfl_xor(p2, m, 64);
                }
                if (r == 0) { atomicAdd(&st[row], p1); atomicAdd(&st[64 + row], p2); }
            }
        }
        gbar(cnt, &bi);
        // ---- St5: x2_raw = relu(LN(x1)) @ fus_w2^T + b2, + stats[2] ----
        {
            const int arow = m0 + r;
            const float* st1 = stats + ((size_t)t * 3 + 1) * 128;
            const float mu = st1[arow] * (1.f / HDIM);
            const float rs = rsqrtf(st1[64 + arow] * (1.f / HDIM) - mu * mu + LN_EPS);
            const float la = rs, lc = -mu * rs;
            const float* xRow = x1f + (size_t)arow * HDIM + kg * 8;
            const bf16_t* Wr = fus_w2b + (size_t)(n0 + r) * HDIM + kg * 8;
            f4 acc = {};
#pragma unroll 4
            for (int k0 = 0; k0 < HDIM; k0 += 32) {
                bf8 a;
#pragma unroll
                for (int j = 0; j < 8; ++j) {
                    const int kj = k0 + kg * 8 + j;
                    a[j] = (__bf16)fmaxf((xRow[k0 + j] * la + lc) * fus_ln1[kj] + fus_ln1[HDIM + kj], 0.f);
                }
                acc = mfma16x16x32(a, *(const bf8*)(Wr + k0), acc);
            }
            const int n = n0 + r;
            const float bz = fus_b2[n];
            float* st = stats + ((size_t)t * 3 + 2) * 128;
#pragma unroll
            for (int i = 0; i < 4; ++i) {
                const int row = m0 + kg * 4 + i;
                const float v = acc[i] + bz;
                x2f[(size_t)row * HDIM + n] = v;
                float p1 = v, p2 = v * v;
#pragma unroll
                for (int m = 1; m < 16; m <<= 1) {
                    p1 += __shfl_xor(p1, m, 64);
                    p2 += __shfl_xor(p2, m, 64);
                }
                if (r == 0) { atomicAdd(&st[row], p1); atomicAdd(&st[64 + row], p2); }
            }
        }
        gbar(cnt, &bi);
        // ---- St6..8: LSTM layers, gates GEMM + fused cell ----
        // Block owns j-range [n0, n0+16) for all 4 gates -> cell is lane-local.
        // Reads: cur[l] (h(t-1), never written this step), nxt[l-1] (written by
        // previous layer, behind a barrier), x2f (layer 0). Writes: nxt[l].
        for (int l = 0; l < NLAY; ++l) {
            const int arow = m0 + r;
            float la = 0.f, lc = 0.f;
            if (l == 0) {
                const float* st2 = stats + ((size_t)t * 3 + 2) * 128;
                const float mu = st2[arow] * (1.f / HDIM);
                const float rs = rsqrtf(st2[64 + arow] * (1.f / HDIM) - mu * mu + LN_EPS);
                la = rs;
                lc = -mu * rs;
            }
            const float* xRow = x2f + (size_t)arow * HDIM + kg * 8;
            const int lprev = (l == 0) ? 0 : (l - 1);
            const bf16_t* h1Row = nxt + (size_t)lprev * LBH + (size_t)arow * HDIM + kg * 8;
            const bf16_t* h2Row = cur + (size_t)l * LBH + (size_t)arow * HDIM + kg * 8;
            const bf16_t* WiB = wihb + (size_t)l * 4 * HDIM * HDIM + (size_t)(n0 + r) * HDIM + kg * 8;
            const bf16_t* WhB = whhb + (size_t)l * 4 * HDIM * HDIM + (size_t)(n0 + r) * HDIM + kg * 8;
            f4 acc0 = {}, acc1 = {}, acc2 = {}, acc3 = {};
#pragma unroll 2
            for (int k0 = 0; k0 < HDIM; k0 += 32) {
                bf8 a1;
                if (l == 0) {
#pragma unroll
                    for (int j = 0; j < 8; ++j) {
                        const int kj = k0 + kg * 8 + j;
                        a1[j] = (__bf16)fmaxf((xRow[k0 + j] * la + lc) * fus_ln2[kj] + fus_ln2[HDIM + kj], 0.f);
                    }
                } else {
                    a1 = *(const bf8*)(h1Row + k0);
                }
                const bf8 a2 = *(const bf8*)(h2Row + k0);
                acc0 = mfma16x16x32(a1, *(const bf8*)(WiB + (size_t)0 * HDIM * HDIM + k0), acc0);
                acc0 = mfma16x16x32(a2, *(const bf8*)(WhB + (size_t)0 * HDIM * HDIM + k0), acc0);
                acc1 = mfma16x16x32(a1, *(const bf8*)(WiB + (size_t)768 * HDIM + k0), acc1);
                acc1 = mfma16x16x32(a2, *(const bf8*)(WhB + (size_t)768 * HDIM + k0), acc1);
                acc2 = mfma16x16x32(a1, *(const bf8*)(WiB + (size_t)1536 * HDIM + k0), acc2);
                acc2 = mfma16x16x32(a2, *(const bf8*)(WhB + (size_t)1536 * HDIM + k0), acc2);
                acc3 = mfma16x16x32(a1, *(const bf8*)(WiB + (size_t)2304 * HDIM + k0), acc3);
                acc3 = mfma16x16x32(a2, *(const bf8*)(WhB + (size_t)2304 * HDIM + k0), acc3);
            }
            const int j = n0 + r;
            const float b0 = bih[l * 3072 + j] + bhh[l * 3072 + j];
            const float b1 = bih[l * 3072 + 768 + j] + bhh[l * 3072 + 768 + j];
            const float b2 = bih[l * 3072 + 1536 + j] + bhh[l * 3072 + 1536 + j];
            const float b3 = bih[l * 3072 + 2304 + j] + bhh[l * 3072 + 2304 + j];
#pragma unroll
            for (int i = 0; i < 4; ++i) {
                const int row = m0 + kg * 4 + i;
                const float iv = sigm(acc0[i] + b0);
                const float fv = sigm(acc1[i] + b1);
                const float gv = tanhf(acc2[i] + b2);
                const float ov = sigm(acc3[i] + b3);
                const size_t idx = (size_t)l * LBH + (size_t)row * HDIM + j;
                const float cn = fv * cst[idx] + iv * gv;
                const float hn = ov * tanhf(cn);
                cst[idx] = cn;
                hst[idx] = hn;
                nxt[idx] = (__bf16)hn;
                if (l == NLAY - 1) HcB[((size_t)t * B_ + row) * HDIM + j] = (__bf16)hn;
            }
            gbar(cnt, &bi);
        }
        // swap h double-buffer (uniform across all threads/blocks)
        bf16_t* tmp = cur; cur = nxt; nxt = tmp;
    }
}

extern "C" void kernel_launch(void* const* d_in, const int* in_sizes, int n_in,
                              void* d_out, int out_size, void* d_ws, size_t ws_size,
                              hipStream_t stream) {
    const int* word_ids  = (const int*)d_in[0];
    const float* cnn     = (const float*)d_in[1];
    const float* attn_f  = (const float*)d_in[2];
    const float* emb     = (const float*)d_in[3];
    const float* af_w    = (const float*)d_in[4];
    const float* af_b    = (const float*)d_in[5];
    const float* qkv_w   = (const float*)d_in[6];
    const float* qkv_b   = (const float*)d_in[7];
    const float* o_w     = (const float*)d_in[8];
    const float* o_b     = (const float*)d_in[9];
    const float* attn_ln = (const float*)d_in[10];
    const float* fus_w1  = (const float*)d_in[11];
    const float* fus_b1  = (const float*)d_in[12];
    const float* fus_ln1 = (const float*)d_in[13];
    const float* fus_w2  = (const float*)d_in[14];
    const float* fus_b2  = (const float*)d_in[15];
    const float* fus_ln2 = (const float*)d_in[16];
    const float* wih     = (const float*)d_in[17];
    const float* whh     = (const float*)d_in[18];
    const float* bih     = (const float*)d_in[19];
    const float* bhh     = (const float*)d_in[20];
    const float* hi_w1   = (const float*)d_in[21];
    const float* hi_b1   = (const float*)d_in[22];
    const float* hi_ln1  = (const float*)d_in[23];
    const float* hi_w2   = (const float*)d_in[24];
    const float* hi_b2   = (const float*)d_in[25];
    const float* hi_ln2  = (const float*)d_in[26];
    const float* ci_w1   = (const float*)d_in[27];
    const float* ci_b1   = (const float*)d_in[28];
    const float* ci_ln1  = (const float*)d_in[29];
    const float* ci_w2   = (const float*)d_in[30];
    const float* ci_b2   = (const float*)d_in[31];
    const float* ci_ln2  = (const float*)d_in[32];
    const float* out_w1  = (const float*)d_in[33];
    const float* out_b1  = (const float*)d_in[34];
    const float* out_ln1 = (const float*)d_in[35];
    const float* out_w2  = (const float*)d_in[36];
    const float* out_b2  = (const float*)d_in[37];
    const float* out_ln2 = (const float*)d_in[38];
    const float* out_w3  = (const float*)d_in[39];
    const float* out_b3  = (const float*)d_in[40];
    float* outf = (float*)d_out;

    // ---- workspace carve (bytes, 256B aligned) ----
    char* wsb = (char*)d_ws;
    size_t off = 0;
    auto allocB = [&](size_t bytes) {
        char* p = wsb + off;
        off += (bytes + 255) & ~(size_t)255;
        return p;
    };
    auto allocF = [&](size_t n) { return (float*)allocB(n * 4); };
    auto allocH = [&](size_t n) { return (bf16_t*)allocB(n * 2); };

    // barrier counter + LN stats (memset to 0 each launch, graph-safe)
    unsigned* barcnt = (unsigned*)allocB(256);
    float* stats     = allocF((size_t)S_ * 3 * 128);   // 48 KiB, contiguous after barcnt

    // bf16 buffers
    bf16_t* featb  = allocH((size_t)3136 * 2048);  // reused post-loop: HcB/Y1B/Y2B
    bf16_t* fpb    = allocH((size_t)3136 * HDIM);
    bf16_t* emb_sb = allocH((size_t)B_ * S_ * 512);
    bf16_t* af_wb  = allocH((size_t)HDIM * 2048);
    bf16_t* qkv_wb = allocH((size_t)3 * HDIM * HDIM);
    bf16_t* o_wb   = allocH((size_t)HDIM * HDIM);
    bf16_t* fus_w1b= allocH((size_t)HDIM * 1280);
    bf16_t* fus_w2b= allocH((size_t)HDIM * HDIM);
    bf16_t* wihb   = allocH((size_t)NLAY * 4 * HDIM * HDIM);
    bf16_t* whhb   = allocH((size_t)NLAY * 4 * HDIM * HDIM);
    bf16_t* hi_w1b = allocH((size_t)1536 * HDIM);
    bf16_t* hi_w2b = allocH((size_t)HDIM * 1536);
    bf16_t* ci_w1b = allocH((size_t)1536 * HDIM);
    bf16_t* ci_w2b = allocH((size_t)HDIM * 1536);
    bf16_t* out_w1b= allocH((size_t)1536 * HDIM);
    bf16_t* out_w2b= allocH((size_t)HDIM * 1536);
    bf16_t* out_w3b= allocH((size_t)V_ * HDIM);
    bf16_t* cnnb   = allocH((size_t)B_ * HDIM);
    bf16_t* hbufA  = allocH((size_t)NLAY * B_ * HDIM);
    bf16_t* hbufB  = allocH((size_t)NLAY * B_ * HDIM);
    bf16_t* tmpB   = allocH((size_t)B_ * 1536);
    bf16_t* ctxB   = allocH((size_t)B_ * HDIM);
    // f32 buffers
    float* Kf      = allocF((size_t)3136 * HDIM);
    float* Vf      = allocF((size_t)3136 * HDIM);
    float* hst     = allocF((size_t)NLAY * B_ * HDIM);
    float* cst     = allocF((size_t)NLAY * B_ * HDIM);
    float* tmp1536 = allocF((size_t)B_ * 1536);
    float* h0b     = allocF((size_t)B_ * HDIM);
    float* c0b     = allocF((size_t)B_ * HDIM);
    float* qb      = allocF((size_t)B_ * HDIM);
    float* ctx2f   = allocF((size_t)B_ * HDIM);
    float* x1f     = allocF((size_t)B_ * HDIM);
    float* x2f     = allocF((size_t)B_ * HDIM);
    float* Y1f     = allocF((size_t)2048 * 1536);  // Y2f aliases (Y1f dead after its LN)
    if (off > ws_size) return;  // visible failure if ws too small

    // post-loop bf16 heads carved inside featb (dead after K/V precompute)
    bf16_t* HcB = featb;                                   // 2048*768
    bf16_t* Y1B = featb + (size_t)2048 * HDIM;             // 2048*1536
    bf16_t* Y2B = Y1B + (size_t)2048 * 1536;               // 2048*768 (total 6.29M <= 6.42M)
    float*  Y2f = Y1f;

    const size_t WQKV = (size_t)HDIM * HDIM;
    const size_t LBH = (size_t)B_ * HDIM;

    // ---- zero barrier + stats (ordered before mega_loop on stream) ----
    hipMemsetAsync(barcnt, 0, 256 + (size_t)S_ * 3 * 128 * 4, stream);

    // ---- all weight casts in one kernel ----
    {
        CastSegs cs;
        const float* srcs[NSEG] = {af_w, qkv_w, o_w, fus_w1, fus_w2, wih, whh,
                                   hi_w1, hi_w2, ci_w1, ci_w2, out_w1, out_w2, out_w3, cnn};
        bf16_t* dsts[NSEG] = {af_wb, qkv_wb, o_wb, fus_w1b, fus_w2b, wihb, whhb,
                              hi_w1b, hi_w2b, ci_w1b, ci_w2b, out_w1b, out_w2b, out_w3b, cnnb};
        const size_t ns[NSEG] = {(size_t)HDIM * 2048, 3 * WQKV, WQKV, (size_t)HDIM * 1280, WQKV,
                                 (size_t)NLAY * 4 * WQKV, (size_t)NLAY * 4 * WQKV,
                                 (size_t)1536 * HDIM, (size_t)HDIM * 1536,
                                 (size_t)1536 * HDIM, (size_t)HDIM * 1536,
                                 (size_t)1536 * HDIM, (size_t)HDIM * 1536,
                                 (size_t)V_ * HDIM, (size_t)B_ * HDIM};
        for (int s = 0; s < NSEG; ++s) {
            cs.src[s] = (const float4*)srcs[s];
            cs.dst[s] = (bf4v*)dsts[s];
            cs.n4[s] = (unsigned)(ns[s] / 4);
        }
        cast_multi<<<2048, 256, 0, stream>>>(cs);
    }

    // ---- precompute ----
    gather_emb<<<B_ * S_, 256, 0, stream>>>(word_ids, emb, emb_sb);
    transpose_feat<<<dim3(64, 2, B_), dim3(32, 8), 0, stream>>>(attn_f, featb);
    gemm_mf<1, 0><<<dim3(12, 49), 256, 0, stream>>>(featb, 2048, af_wb, 2048, af_b, fpb, HDIM, 2048);
    gemm_mf<0, 0><<<dim3(12, 49), 256, 0, stream>>>(fpb, HDIM, qkv_wb + WQKV, HDIM, qkv_b + HDIM, Kf, HDIM, HDIM);
    gemm_mf<0, 0><<<dim3(12, 49), 256, 0, stream>>>(fpb, HDIM, qkv_wb + 2 * WQKV, HDIM, qkv_b + 2 * HDIM, Vf, HDIM, HDIM);
    // h0 / c0 init MLPs
    gemm_mf<0, 0><<<dim3(24, 1), 256, 0, stream>>>(cnnb, HDIM, hi_w1b, HDIM, hi_b1, tmp1536, 1536, HDIM);
    ln_act<<<B_, 256, 0, stream>>>(tmp1536, hi_ln1, tmp1536, tmpB, 1536, 1);
    gemm_mf<0, 0><<<dim3(12, 1), 256, 0, stream>>>(tmpB, 1536, hi_w2b, 1536, hi_b2, h0b, HDIM, 1536);
    ln_act<<<B_, 256, 0, stream>>>(h0b, hi_ln2, h0b, nullptr, HDIM, 2);
    gemm_mf<0, 0><<<dim3(24, 1), 256, 0, stream>>>(cnnb, HDIM, ci_w1b, HDIM, ci_b1, tmp1536, 1536, HDIM);
    ln_act<<<B_, 256, 0, stream>>>(tmp1536, ci_ln1, tmp1536, tmpB, 1536, 1);
    gemm_mf<0, 0><<<dim3(12, 1), 256, 0, stream>>>(tmpB, 1536, ci_w2b, 1536, ci_b2, c0b, HDIM, 1536);
    ln_act<<<B_, 256, 0, stream>>>(c0b, ci_ln2, c0b, nullptr, HDIM, 2);
    tile_state<<<192, 256, 0, stream>>>(h0b, c0b, hst, cst, hbufA);

    // ---- entire 32-step recurrence: ONE kernel ----
    mega_loop<<<NBLK, 256, 0, stream>>>(
        qkv_wb, qkv_b, Kf, Vf, o_wb, o_b, attn_ln, emb_sb,
        fus_w1b, fus_b1, fus_ln1, fus_w2b, fus_b2, fus_ln2,
        wihb, whhb, bih, bhh,
        hst, cst, hbufA, hbufB, qb, ctxB, ctx2f, x1f, x2f,
        stats, HcB, barcnt);

    // ---- deferred output head (2048 rows batched) ----
    gemm_mf<0, 0><<<dim3(24, 32), 256, 0, stream>>>(HcB, HDIM, out_w1b, HDIM, out_b1, Y1f, 1536, HDIM);
    ln_act<<<B_ * S_, 256, 0, stream>>>(Y1f, out_ln1, Y1f, Y1B, 1536, 1);
    gemm_mf<0, 0><<<dim3(12, 32), 256, 0, stream>>>(Y1B, 1536, out_w2b, 1536, out_b2, Y2f, HDIM, 1536);
    ln_act<<<B_ * S_, 256, 0, stream>>>(Y2f, out_ln2, Y2f, Y2B, HDIM, 1);
    gemm_mf<0, 1><<<dim3(500, 32), 256, 0, stream>>>(Y2B, HDIM, out_w3b, HDIM, out_b3, outf, V_, HDIM);

    // ---- final states ----
    size_t ys_elems = (size_t)B_ * S_ * V_;
    hipMemcpyAsync(outf + ys_elems, hst, NLAY * LBH * sizeof(float), hipMemcpyDeviceToDevice, stream);
    hipMemcpyAsync(outf + ys_elems + NLAY * LBH, cst, NLAY * LBH * sizeof(float), hipMemcpyDeviceToDevice, stream);
}